// Round 13
// baseline (746.488 us; speedup 1.0000x reference)
//
#include <hip/hip_runtime.h>
#include <hip/hip_fp16.h>
#include <stdint.h>

// Bidirectional LSTM: N=1024, T=512, H=128; enc 2->128->128; dec 256->128->1.
// fp16 MFMA (fp32 accum). ws = 256 MiB:
//   bufA 128MiB: feat -> overwritten in place with relu(h_fw)   [t][n][128] fp16
//   bufB 128MiB: feat -> overwritten in place with relu(h_bw)   [t][n][128] fp16
// Round-13 LSTM: producer/consumer wave roles, BULK-SYNCHRONOUS (r12's async
// counters replaced by __syncthreads double-buffering — isolates r12's failure:
// if indexing is right this must be bit-identical to r7's 2.441406e-4).
//   256 blocks x 512 thr, 8 chains/block. Waves 4-7 (producers): xpart =
//   feat@Wih for the NEXT step-pair, full 16-row M-tiles (8 chains x 2 steps,
//   zero M-waste) -> fp32 LDS slot. Waves 0-3 (consumers): C-in from slot,
//   add h@Whh, elementwise, h out. Producer MFMAs are independent of consumer
//   VALU within each barrier interval -> SIMD can overlap the two pipes.

#define TN 512
#define NB 1024

typedef __attribute__((ext_vector_type(8))) _Float16 f16x8;
typedef __attribute__((ext_vector_type(4))) float f32x4;

#define MFMA16(a,b,c) __builtin_amdgcn_mfma_f32_16x16x32_f16(a,b,c,0,0,0)
#define RCP(x) __builtin_amdgcn_rcpf(x)

__device__ __forceinline__ f16x8 cvt_frag(const float* p){
  f32x4 a = *(const f32x4*)p;
  f32x4 b = *(const f32x4*)(p+4);
  f16x8 h;
  h[0]=(_Float16)a[0]; h[1]=(_Float16)a[1]; h[2]=(_Float16)a[2]; h[3]=(_Float16)a[3];
  h[4]=(_Float16)b[0]; h[5]=(_Float16)b[1]; h[6]=(_Float16)b[2]; h[7]=(_Float16)b[3];
  return h;
}

__device__ __forceinline__ unsigned short f2h(float f){
  return __half_as_ushort(__float2half(f));
}

// ---------------- K0: encoder -> feat fp16 [t][n][128], written to BOTH copies ----------------
__global__ __launch_bounds__(256) void enc_kernel(
    const float* __restrict__ x,  const float* __restrict__ e1w,
    const float* __restrict__ e1b,const float* __restrict__ e2w,
    const float* __restrict__ e2b,
    unsigned short* __restrict__ featA, unsigned short* __restrict__ featB)
{
  __shared__ float xs[64][2];
  __shared__ unsigned int A32[64][68];   // r1 fp16 pairs, row stride 272B
  int tid = threadIdx.x;
  long rowbase = (long)blockIdx.x * 64;  // row = t*1024 + n
  if (tid < 128){
    int i = tid >> 1, cc = tid & 1;
    long row = rowbase + i;
    int t = (int)(row >> 10), n = (int)(row & 1023);
    xs[i][cc] = x[((size_t)n * TN + t) * 2 + cc];
  }
  int w4 = tid >> 6, lane = tid & 63, lq = lane >> 4, lr = lane & 15;
  f16x8 Bf[2][4];
  float b2v[2];
  #pragma unroll
  for (int nt2 = 0; nt2 < 2; nt2++){
    int col = (w4*2 + nt2)*16 + lr;
    b2v[nt2] = e2b[col];
    #pragma unroll
    for (int ks = 0; ks < 4; ks++)
      Bf[nt2][ks] = cvt_frag(e2w + col*128 + ks*32 + lq*8);
  }
  int q = tid >> 6, dp = tid & 63;
  float w00 = e1w[4*dp], w01 = e1w[4*dp+1], w10 = e1w[4*dp+2], w11 = e1w[4*dp+3];
  float b0 = e1b[2*dp], b1 = e1b[2*dp+1];
  __syncthreads();
  #pragma unroll
  for (int rr = 0; rr < 16; rr++){
    int r = q*16 + rr;
    float x0 = xs[r][0], x1 = xs[r][1];
    float v0 = fmaxf(w00*x0 + w01*x1 + b0, 0.f);
    float v1 = fmaxf(w10*x0 + w11*x1 + b1, 0.f);
    A32[r][dp] = (unsigned int)f2h(v0) | ((unsigned int)f2h(v1) << 16);
  }
  __syncthreads();
  #pragma unroll
  for (int Mt = 0; Mt < 4; Mt++){
    f16x8 ah[4];
    #pragma unroll
    for (int ks = 0; ks < 4; ks++)
      ah[ks] = *(const f16x8*)((const unsigned short*)&A32[Mt*16+lr][0] + ks*32 + lq*8);
    f32x4 acc0 = {0.f,0.f,0.f,0.f}, acc1 = {0.f,0.f,0.f,0.f};
    #pragma unroll
    for (int ks = 0; ks < 4; ks++){
      acc0 = MFMA16(ah[ks], Bf[0][ks], acc0);
      acc1 = MFMA16(ah[ks], Bf[1][ks], acc1);
    }
    #pragma unroll
    for (int r = 0; r < 4; r++){
      size_t row = (size_t)(rowbase + Mt*16 + lq*4 + r);
      unsigned short v0 = f2h(acc0[r] + b2v[0]);
      unsigned short v1 = f2h(acc1[r] + b2v[1]);
      featA[row*128 + (w4*2+0)*16 + lr] = v0;
      featA[row*128 + (w4*2+1)*16 + lr] = v1;
      featB[row*128 + (w4*2+0)*16 + lr] = v0;
      featB[row*128 + (w4*2+1)*16 + lr] = v1;
    }
  }
}

// ---------------- K1: persistent bidirectional LSTM (bulk-sync producer/consumer) ----------------
// 256 blocks x 512 thr; block b: dir=b>>7, chains n0..n0+7.
// slotf[slot][stepofs][gate*12 + chain]: xpart fp32, slot = pair parity.
// Producer pair tile: A rows R -> (chain R&7, step-ofs R>>3); C rows lq*4+r.
__global__ __launch_bounds__(512, 2) void lstm_kernel(
    unsigned short* bufA, unsigned short* bufB,
    const float* __restrict__ wih, const float* __restrict__ whh)
{
  __shared__ __align__(16) float slotf[2][2][6144];          // 98304 B
  __shared__ __align__(16) unsigned short hbS[2][16][136];   // 8704 B; rows 8-15 stay 0
  int tid = threadIdx.x, b = blockIdx.x;
  int dir = b >> 7, n0 = (b & 127) << 3;
  int w = tid >> 6, lane = tid & 63, lq = lane >> 4, lr = lane & 15;
  unsigned short* buf = dir ? bufB : bufA;
  long dstep = dir ? -(long)(NB*128) : (long)(NB*128);
  long t0 = dir ? (TN-1) : 0;
  const f32x4 zero4 = {0.f, 0.f, 0.f, 0.f};

  for (int i = tid; i < 2176; i += 512) ((unsigned int*)hbS)[i] = 0u;

  if (w >= 4){
    // ---------------- PRODUCER wave pw: gate block [pw*128, pw*128+128) ----------------
    int pw = w - 4;
    f16x8 bw[8][4];
    #pragma unroll
    for (int j = 0; j < 8; j++){
      #pragma unroll
      for (int ks = 0; ks < 4; ks++)
        bw[j][ks] = cvt_frag(wih + (size_t)(pw*128 + j*16 + lr)*128 + ks*32 + lq*8);
    }
    // A row lr: chain lr&7, step-ofs lr>>3
    const unsigned short* fpp = buf + ((size_t)t0*NB + n0 + (lr & 7))*128
                              + (long)(lr >> 3)*dstep + lq*8;
    __syncthreads();                       // init barrier
    { // prologue: pair 0 -> slot 0
      uint4 pa[4];
      #pragma unroll
      for (int ks = 0; ks < 4; ks++) pa[ks] = *(const uint4*)(fpp + ks*32);
      fpp += 2*dstep;
      float* sb = &slotf[0][lq >> 1][0] + (lq & 1)*4;
      #pragma unroll
      for (int j = 0; j < 8; j++){
        f32x4 a = MFMA16(*(const f16x8*)&pa[0], bw[j][0], zero4);
        #pragma unroll
        for (int ks = 1; ks < 4; ks++) a = MFMA16(*(const f16x8*)&pa[ks], bw[j][ks], a);
        *(f32x4*)(sb + (size_t)(pw*128 + j*16 + lr)*12) = a;
      }
    }
    __syncthreads();                       // prologue barrier
    for (int p = 0; p < 256; p++){
      // produce pair p+1 into slot (p&1)^1; last iter reads t +/- 512..513:
      // fw lands at bufB start, bw at bufA end — inside ws, values dead.
      float* sb = &slotf[(p & 1) ^ 1][lq >> 1][0] + (lq & 1)*4;
      uint4 pa[4];
      #pragma unroll
      for (int ks = 0; ks < 4; ks++) pa[ks] = *(const uint4*)(fpp + ks*32);
      fpp += 2*dstep;
      #pragma unroll
      for (int j = 0; j < 4; j++){
        f32x4 a = MFMA16(*(const f16x8*)&pa[0], bw[j][0], zero4);
        #pragma unroll
        for (int ks = 1; ks < 4; ks++) a = MFMA16(*(const f16x8*)&pa[ks], bw[j][ks], a);
        *(f32x4*)(sb + (size_t)(pw*128 + j*16 + lr)*12) = a;
      }
      __syncthreads();                     // mid barrier
      #pragma unroll
      for (int j = 4; j < 8; j++){
        f32x4 a = MFMA16(*(const f16x8*)&pa[0], bw[j][0], zero4);
        #pragma unroll
        for (int ks = 1; ks < 4; ks++) a = MFMA16(*(const f16x8*)&pa[ks], bw[j][ks], a);
        *(f32x4*)(sb + (size_t)(pw*128 + j*16 + lr)*12) = a;
      }
      __syncthreads();                     // end barrier
    }
  } else {
    // ---------------- CONSUMER wave cw: gates G*128 + cw*32 + dt*16 + lr ----------------
    int cw = w;
    f16x8 bh[4][2][4];
    #pragma unroll
    for (int G = 0; G < 4; G++){
      #pragma unroll
      for (int dt = 0; dt < 2; dt++){
        #pragma unroll
        for (int ks = 0; ks < 4; ks++)
          bh[G][dt][ks] = cvt_frag(whh + (size_t)(G*128 + cw*32 + dt*16 + lr)*128 + ks*32 + lq*8);
      }
    }
    int chb = ((lane >> 4) & 1) * 4;               // chain base after redistribution
    int dim = 32*cw + (lane >> 5)*16 + lr;         // hidden dim owned
    unsigned short* op = buf + ((size_t)t0*NB + n0 + chb)*128 + dim;
    float c4[4] = {0.f, 0.f, 0.f, 0.f};

#define CONSUME(SP) do { \
      f16x8 ah[4]; \
      _Pragma("unroll") \
      for (int ks = 0; ks < 4; ks++) ah[ks] = *(const f16x8*)&hbS[SP][lr][ks*32 + lq*8]; \
      const float* sb = &slotf[p & 1][SP][0] + (lq & 1)*4; \
      f32x4 acc[4][2]; \
      _Pragma("unroll") \
      for (int G = 0; G < 4; G++){ \
        _Pragma("unroll") \
        for (int dt = 0; dt < 2; dt++){ \
          acc[G][dt] = *(const f32x4*)(sb + (size_t)(G*128 + cw*32 + dt*16 + lr)*12); \
          _Pragma("unroll") \
          for (int ks = 0; ks < 4; ks++) \
            acc[G][dt] = MFMA16(ah[ks], bh[G][dt][ks], acc[G][dt]); \
        } \
      } \
      f32x4 av[4]; \
      _Pragma("unroll") \
      for (int G = 0; G < 4; G++){ \
        _Pragma("unroll") \
        for (int r = 0; r < 4; r++){ \
          float sw = __shfl_xor(acc[G][1][r], 32); \
          av[G][r] = (lane < 32) ? acc[G][0][r] : sw; \
        } \
      } \
      _Pragma("unroll") \
      for (int r = 0; r < 4; r++){ \
        float iv = av[0][r], fv = av[1][r], gv = av[2][r], ov = av[3][r]; \
        float si = RCP(1.f + __expf(-iv)); \
        float sf = RCP(1.f + __expf(-fv)); \
        float so = RCP(1.f + __expf(-ov)); \
        float tg = 1.f - 2.f*RCP(__expf(2.f*gv) + 1.f); \
        c4[r] = sf*c4[r] + si*tg; \
        float tc = 1.f - 2.f*RCP(__expf(2.f*c4[r]) + 1.f); \
        float hv = so*tc; \
        unsigned short hh = f2h(hv); \
        hbS[(SP)^1][chb + r][dim] = hh; \
        op[r*128] = (hv > 0.f) ? hh : (unsigned short)0; \
      } \
      op += dstep; \
    } while(0)

    __syncthreads();                       // init barrier
    __syncthreads();                       // prologue barrier (slot 0 ready)
    for (int p = 0; p < 256; p++){
      CONSUME(0);                          // step 2p
      __syncthreads();                     // mid barrier
      CONSUME(1);                          // step 2p+1
      __syncthreads();                     // end barrier
    }
#undef CONSUME
  }
}

// ---------------- K2: decoder (fp16 MFMA, K=256); inputs already relu'd ----------------
__global__ __launch_bounds__(256) void dec_kernel(
    const unsigned short* __restrict__ hfw, const unsigned short* __restrict__ hbw,
    const float* __restrict__ d1w, const float* __restrict__ d1b,
    const float* __restrict__ d2w, const float* __restrict__ d2b,
    float* __restrict__ out)
{
  __shared__ unsigned short A[64][264];  // [hfw||hbw], row stride 528B
  __shared__ float partial[4][64];
  int tid = threadIdx.x;
  long rowbase = (long)blockIdx.x * 64;
  #pragma unroll
  for (int u = 0; u < 8; u++){
    int chunk = u*256 + tid;             // 0..2047
    int row = chunk >> 5, seg = chunk & 31;
    const unsigned short* src = (seg < 16)
        ? (hfw + ((size_t)(rowbase + row))*128 + seg*8)
        : (hbw + ((size_t)(rowbase + row))*128 + (seg-16)*8);
    *(uint4*)&A[row][seg*8] = *(const uint4*)src;
  }
  int w4 = tid >> 6, lane = tid & 63, lq = lane >> 4, lr = lane & 15;
  f16x8 Bf[2][8];
  float b1v[2], w2v[2];
  #pragma unroll
  for (int nt2 = 0; nt2 < 2; nt2++){
    int col = (w4*2 + nt2)*16 + lr;
    b1v[nt2] = d1b[col];
    w2v[nt2] = d2w[col];
    #pragma unroll
    for (int ks = 0; ks < 8; ks++)
      Bf[nt2][ks] = cvt_frag(d1w + col*256 + ks*32 + lq*8);
  }
  float b2s = d2b[0];
  __syncthreads();
  #pragma unroll
  for (int Mt = 0; Mt < 4; Mt++){
    f16x8 ah[8];
    #pragma unroll
    for (int ks = 0; ks < 8; ks++)
      ah[ks] = *(const f16x8*)&A[Mt*16+lr][ks*32 + lq*8];
    f32x4 acc0 = {0.f,0.f,0.f,0.f}, acc1 = {0.f,0.f,0.f,0.f};
    #pragma unroll
    for (int ks = 0; ks < 8; ks++){
      acc0 = MFMA16(ah[ks], Bf[0][ks], acc0);
      acc1 = MFMA16(ah[ks], Bf[1][ks], acc1);
    }
    #pragma unroll
    for (int r = 0; r < 4; r++){
      float p = fmaxf(acc0[r] + b1v[0], 0.f) * w2v[0]
              + fmaxf(acc1[r] + b1v[1], 0.f) * w2v[1];
      p += __shfl_xor(p, 1);
      p += __shfl_xor(p, 2);
      p += __shfl_xor(p, 4);
      p += __shfl_xor(p, 8);
      if (lr == 0) partial[w4][Mt*16 + lq*4 + r] = p;
    }
  }
  __syncthreads();
  if (tid < 64){
    long row = rowbase + tid;
    int t = (int)(row >> 10), n = (int)(row & 1023);
    out[(size_t)n*TN + t] = partial[0][tid] + partial[1][tid]
                          + partial[2][tid] + partial[3][tid] + b2s;
  }
}

extern "C" void kernel_launch(void* const* d_in, const int* in_sizes, int n_in,
                              void* d_out, int out_size, void* d_ws, size_t ws_size,
                              hipStream_t stream)
{
  const float* x   = (const float*)d_in[0];
  const float* e1w = (const float*)d_in[1];
  const float* e1b = (const float*)d_in[2];
  const float* e2w = (const float*)d_in[3];
  const float* e2b = (const float*)d_in[4];
  const float* wih = (const float*)d_in[5];
  const float* whh = (const float*)d_in[6];
  const float* d1w = (const float*)d_in[7];
  const float* d1b = (const float*)d_in[8];
  const float* d2w = (const float*)d_in[9];
  const float* d2b = (const float*)d_in[10];
  float* out = (float*)d_out;

  if (ws_size < ((size_t)256 << 20)) return;   // ws guard (rounds 1-2 crashed on ws overflow)

  char* ws = (char*)d_ws;
  unsigned short* bufA = (unsigned short*)ws;                            // 128 MiB
  unsigned short* bufB = (unsigned short*)(ws + (((size_t)128) << 20));  // 128 MiB

  hipLaunchKernelGGL(enc_kernel, dim3(8192), dim3(256), 0, stream, x, e1w, e1b, e2w, e2b, bufA, bufB);
  hipLaunchKernelGGL(lstm_kernel, dim3(256), dim3(512), 0, stream, bufA, bufB, wih, whh);
  hipLaunchKernelGGL(dec_kernel, dim3(8192), dim3(256), 0, stream, bufA, bufB, d1w, d1b, d2w, d2b, out);
}